// Round 1
// baseline (3429.050 us; speedup 1.0000x reference)
//
#include <hip/hip_runtime.h>
#include <math.h>

#define BSZ 32          // leaf block size
#define CH  256         // channels
#define NH  4           // heads
#define HD  64          // head dim

// ---------------- kernel 1: per-cell winning edge (last write wins) -------
__global__ void edge_win_kernel(const int* __restrict__ ei, int E, int nb,
                                int* __restrict__ win) {
    int e = blockIdx.x * blockDim.x + threadIdx.x;
    if (e >= E) return;
    int r = ei[e];
    int c = ei[E + e];
    int br = r >> 5, bc = c >> 5;
    if (br == bc && br < nb) {
        // NumPy indexed-assignment semantics: the LAST duplicate wins.
        // atomicMax over the edge index selects exactly that edge.
        atomicMax(&win[br * (BSZ * BSZ) + (r & 31) * BSZ + (c & 31)], e);
    }
}

// ---------------- kernel 2: fused per-block attention ---------------------
__global__ __launch_bounds__(256, 1)
void leaf_attn_kernel(const float* __restrict__ x,
                      const int*   __restrict__ ei,
                      const float* __restrict__ ev,
                      const float* __restrict__ pos,
                      const float* __restrict__ qkv_w,
                      const float* __restrict__ qkv_b,
                      const float* __restrict__ proj_w,
                      const float* __restrict__ proj_b,
                      const float* __restrict__ gate_w,
                      const float* __restrict__ gate_b,
                      const int*   __restrict__ win,
                      float* __restrict__ out,
                      int E, int nb)
{
    // LDS plan (155,264 B total):
    //   xs : x rows 0..31 + mean row 32        (33*256 f32)  -> reused as comb[32][4][33]
    //   qs : q rows 0..31                      (32*256 f32)  -> reused as x_out
    //   ks : k rows 0..32                      (33*256 f32)
    //   vs : v rows 0..32                      (33*256 f32)
    //   ef4: physics features per (qi,kj)      (32*33*4 f32)
    //   bias: additive score bias, -inf = masked (32*33 f32)
    __shared__ float xs[33 * CH];
    __shared__ float qs[BSZ * CH];
    __shared__ float ks[33 * CH];
    __shared__ float vs[33 * CH];
    __shared__ float ef4[BSZ * 33 * 4];
    __shared__ float bias[BSZ * 33];

    const int b = blockIdx.x;
    const int t = threadIdx.x;          // 0..255, acts as channel index in GEMM phases
    const int base_row = b * BSZ;

    // ---- load x block (coalesced) ----
    for (int r = 0; r < BSZ; ++r)
        xs[r * CH + t] = x[(size_t)(base_row + r) * CH + t];
    __syncthreads();

    // ---- mean row (block node) ----
    {
        float s = 0.f;
        #pragma unroll
        for (int r = 0; r < BSZ; ++r) s += xs[r * CH + t];
        xs[BSZ * CH + t] = s * (1.0f / BSZ);
    }

    // ---- connectivity: bias + edge features per (qi,kj) cell ----
    for (int p = t; p < BSZ * 33; p += 256) {
        int qi = p / 33, kj = p % 33;
        float v0 = 0.f, v1 = 0.f, v2 = 0.f, v3 = 0.f, bv;
        if (kj == BSZ || kj == qi) {          // block-node col or diagonal
            v3 = 1.0f; bv = 1.0f;
        } else {
            int w = win[b * (BSZ * BSZ) + qi * BSZ + kj];
            if (w >= 0) {
                int rr = ei[w], cc = ei[E + w];
                v0 = pos[cc * 3 + 0] - pos[rr * 3 + 0];
                v1 = pos[cc * 3 + 1] - pos[rr * 3 + 1];
                v2 = pos[cc * 3 + 2] - pos[rr * 3 + 2];
                v3 = ev[w];
                bv = v3;
            } else {
                bv = -INFINITY;               // masked
            }
        }
        ef4[p * 4 + 0] = v0; ef4[p * 4 + 1] = v1;
        ef4[p * 4 + 2] = v2; ef4[p * 4 + 3] = v3;
        bias[p] = bv;
    }
    __syncthreads();

    // ---- qkv GEMM: thread t owns output channel t of q, k, v -------------
    {
        float accq[BSZ];
        float acck[33];
        float accv[33];
        #pragma unroll
        for (int r = 0; r < BSZ; ++r) accq[r] = 0.f;
        #pragma unroll
        for (int r = 0; r < 33; ++r) { acck[r] = 0.f; accv[r] = 0.f; }

        const float4* wq4 = (const float4*)(qkv_w + (size_t)t * CH);
        const float4* wk4 = (const float4*)(qkv_w + (size_t)(CH + t) * CH);
        const float4* wv4 = (const float4*)(qkv_w + (size_t)(2 * CH + t) * CH);

        for (int i4 = 0; i4 < CH / 4; ++i4) {
            float4 wq = wq4[i4], wk = wk4[i4], wv = wv4[i4];
            #pragma unroll
            for (int r = 0; r < 33; ++r) {
                float4 xv = *(const float4*)&xs[r * CH + i4 * 4];  // LDS broadcast
                acck[r] += xv.x * wk.x + xv.y * wk.y + xv.z * wk.z + xv.w * wk.w;
                accv[r] += xv.x * wv.x + xv.y * wv.y + xv.z * wv.z + xv.w * wv.w;
                if (r < BSZ)
                    accq[r] += xv.x * wq.x + xv.y * wq.y + xv.z * wq.z + xv.w * wq.w;
            }
        }
        float bq = qkv_b[t], bk = qkv_b[CH + t], bv = qkv_b[2 * CH + t];
        #pragma unroll
        for (int r = 0; r < BSZ; ++r) qs[r * CH + t] = accq[r] + bq;
        #pragma unroll
        for (int r = 0; r < 33; ++r) {
            ks[r * CH + t] = acck[r] + bk;
            vs[r * CH + t] = accv[r] + bv;
        }
    }
    __syncthreads();

    // ---- scores: comb[qi][h][kj] = 0.125 * q.k + bias (bias=-inf masks) --
    float* comb = xs;  // x data dead; 32*4*33 = 4224 floats fits in xs
    for (int p = t; p < BSZ * 33; p += 256) {
        int qi = p / 33, kj = p % 33;
        float bb = bias[p];
        #pragma unroll
        for (int h = 0; h < NH; ++h) {
            float s = 0.f;
            #pragma unroll
            for (int i4 = 0; i4 < HD / 4; ++i4) {
                float4 qv = *(const float4*)&qs[qi * CH + h * HD + i4 * 4];
                float4 kv = *(const float4*)&ks[kj * CH + h * HD + i4 * 4];
                s += qv.x * kv.x + qv.y * kv.y + qv.z * kv.z + qv.w * kv.w;
            }
            comb[(qi * NH + h) * 33 + kj] = s * 0.125f + bb;
        }
    }
    __syncthreads();

    // ---- softmax over kj + gate; comb := probs + gate --------------------
    if (t < BSZ * NH) {
        int qi = t >> 2, h = t & 3;
        float* row = comb + (qi * NH + h) * 33;
        float m = -INFINITY;
        #pragma unroll
        for (int kj = 0; kj < 33; ++kj) m = fmaxf(m, row[kj]);
        float e[33];
        float sum = 0.f;
        #pragma unroll
        for (int kj = 0; kj < 33; ++kj) { e[kj] = expf(row[kj] - m); sum += e[kj]; }
        float inv = 1.0f / sum;
        float gw0 = gate_w[h * 4 + 0], gw1 = gate_w[h * 4 + 1];
        float gw2 = gate_w[h * 4 + 2], gw3 = gate_w[h * 4 + 3];
        float gb = gate_b[h];
        #pragma unroll
        for (int kj = 0; kj < 33; ++kj) {
            float g = 0.f;
            float bb = bias[qi * 33 + kj];
            if (bb != -INFINITY) {            // unmasked
                const float* f = &ef4[(qi * 33 + kj) * 4];
                g = f[0] * gw0 + f[1] * gw1 + f[2] * gw2 + f[3] * gw3 + gb;
            }
            row[kj] = e[kj] * inv + g;
        }
    }
    __syncthreads();

    // ---- PV: x_out[qi][t] = sum_kj comb[qi][h][kj] * v[kj][t] ------------
    {
        int h = t >> 6;
        float acc[BSZ];
        #pragma unroll
        for (int r = 0; r < BSZ; ++r) acc[r] = 0.f;
        for (int kj = 0; kj < 33; ++kj) {
            float vv = vs[kj * CH + t];
            #pragma unroll
            for (int qi = 0; qi < BSZ; ++qi)
                acc[qi] += comb[(qi * NH + h) * 33 + kj] * vv;
        }
        float* xo = qs;  // q dead; reuse as x_out
        #pragma unroll
        for (int qi = 0; qi < BSZ; ++qi) xo[qi * CH + t] = acc[qi];
    }
    __syncthreads();

    // ---- proj: out[r][t] = x_out[r][:] . proj_w[t][:] + proj_b[t] --------
    {
        const float* xo = qs;
        float acc[BSZ];
        #pragma unroll
        for (int r = 0; r < BSZ; ++r) acc[r] = 0.f;
        const float4* w4 = (const float4*)(proj_w + (size_t)t * CH);
        for (int i4 = 0; i4 < CH / 4; ++i4) {
            float4 w = w4[i4];
            #pragma unroll
            for (int r = 0; r < BSZ; ++r) {
                float4 xv = *(const float4*)&xo[r * CH + i4 * 4];  // broadcast
                acc[r] += xv.x * w.x + xv.y * w.y + xv.z * w.z + xv.w * w.w;
            }
        }
        float pb = proj_b[t];
        #pragma unroll
        for (int r = 0; r < BSZ; ++r)
            out[(size_t)(base_row + r) * CH + t] = acc[r] + pb;
    }
}

extern "C" void kernel_launch(void* const* d_in, const int* in_sizes, int n_in,
                              void* d_out, int out_size, void* d_ws, size_t ws_size,
                              hipStream_t stream) {
    const float* x      = (const float*)d_in[0];
    const int*   ei     = (const int*)  d_in[1];
    const float* ev     = (const float*)d_in[2];
    const float* pos    = (const float*)d_in[3];
    const float* qkv_w  = (const float*)d_in[4];
    const float* qkv_b  = (const float*)d_in[5];
    const float* proj_w = (const float*)d_in[6];
    const float* proj_b = (const float*)d_in[7];
    const float* gate_w = (const float*)d_in[8];
    const float* gate_b = (const float*)d_in[9];
    float* out = (float*)d_out;

    const int E  = in_sizes[2];          // edge count (edge_values)
    const int N  = in_sizes[0] / CH;     // node count
    const int nb = N / BSZ;              // leaf blocks

    int* win = (int*)d_ws;               // nb*32*32 ints = 16.8 MB
    hipMemsetAsync(win, 0xFF, (size_t)nb * BSZ * BSZ * sizeof(int), stream);
    edge_win_kernel<<<(E + 255) / 256, 256, 0, stream>>>(ei, E, nb, win);
    leaf_attn_kernel<<<nb, 256, 0, stream>>>(x, ei, ev, pos, qkv_w, qkv_b,
                                             proj_w, proj_b, gate_w, gate_b,
                                             win, out, E, nb);
}

// Round 2
// 420.608 us; speedup vs baseline: 8.1526x; 8.1526x over previous
//
#include <hip/hip_runtime.h>
#include <math.h>

#define BSZ 32
#define CH  256
#define NH  4
#define HD  64
#define SC_STRIDE 35   // score scratch row stride (f32 words): 3*qi mod 32 spreads banks

typedef short  bf16x8 __attribute__((ext_vector_type(8)));
typedef float  f32x4  __attribute__((ext_vector_type(4)));
typedef unsigned short ushort_t;
typedef unsigned int   uint_t;

#define MFMA(a, b, c) __builtin_amdgcn_mfma_f32_16x16x32_bf16((a), (b), (c), 0, 0, 0)

__device__ __forceinline__ ushort_t f2b(float f) {
    uint_t u = __builtin_bit_cast(uint_t, f);
    uint_t r = (u + 0x7FFFu + ((u >> 16) & 1u)) >> 16;   // RTNE
    return (ushort_t)r;
}
__device__ __forceinline__ float b2f(ushort_t u) {
    uint_t v = ((uint_t)u) << 16;
    return __builtin_bit_cast(float, v);
}
__device__ __forceinline__ uint_t pk2(float a, float b) {
    return (uint_t)f2b(a) | ((uint_t)f2b(b) << 16);
}

// ---------------- kernel 1: per-cell winning edge (last write wins) -------
__global__ void edge_win_kernel(const int* __restrict__ ei, int E, int nb,
                                int* __restrict__ win) {
    int e = blockIdx.x * blockDim.x + threadIdx.x;
    if (e >= E) return;
    int r = ei[e];
    int c = ei[E + e];
    int br = r >> 5, bc = c >> 5;
    if (br == bc && br < nb) {
        atomicMax(&win[br * (BSZ * BSZ) + (r & 31) * BSZ + (c & 31)], e);
    }
}

// ---------------- kernel 2: fp32 -> bf16 weight conversion ----------------
__global__ void wconv_kernel(const float* __restrict__ qkv_w,
                             const float* __restrict__ proj_w,
                             ushort_t* __restrict__ qkv_wb,
                             ushort_t* __restrict__ proj_wb) {
    int i = blockIdx.x * blockDim.x + threadIdx.x;
    if (i < 768 * 256) qkv_wb[i] = f2b(qkv_w[i]);
    if (i < 256 * 256) proj_wb[i] = f2b(proj_w[i]);
}

// ---------------- kernel 3: fused per-block attention (MFMA) --------------
// LDS regions (80192 B total -> 2 blocks/CU):
//   off 0     : xb bf16[32][256] swz8  ->  scf f32[4][32][SC_STRIDE]  ->  comb bf16[4][32][32] swz4
//   off 17920 : qb bf16[32][256] swz8
//   off 34304 : kb bf16[32][256] swz8  ->  xo (x_out) bf16[32][256] swz8
//   off 50688 : vT bf16[256][32] swz4 (kj within row swizzled by (c&3)<<3)
//   off 67072 : krow32 f32[256]
//   off 68096 : vrow32 f32[256]
//   off 69120 : comb32 f32[4][32]
//   off 69632 : gate4  bf16[32*33][4]
//   off 78080 : sbias  bf16[32*33]
__global__ __launch_bounds__(256, 2)
void leaf_attn_mfma(const float* __restrict__ x,
                    const int*   __restrict__ ei,
                    const float* __restrict__ ev,
                    const float* __restrict__ pos,
                    const ushort_t* __restrict__ qkv_wb,
                    const float* __restrict__ qkv_b,
                    const ushort_t* __restrict__ proj_wb,
                    const float* __restrict__ proj_b,
                    const float* __restrict__ gate_w,
                    const float* __restrict__ gate_b,
                    const int*   __restrict__ win,
                    float* __restrict__ out,
                    int E, int nb)
{
    __shared__ __align__(16) char smem[80192];
    ushort_t* xb     = (ushort_t*)(smem);
    float*    scf    = (float*)(smem);
    ushort_t* comb   = (ushort_t*)(smem);
    ushort_t* qb     = (ushort_t*)(smem + 17920);
    ushort_t* kb     = (ushort_t*)(smem + 34304);
    ushort_t* xo     = (ushort_t*)(smem + 34304);
    ushort_t* vT     = (ushort_t*)(smem + 50688);
    float*    krow32 = (float*)(smem + 67072);
    float*    vrow32 = (float*)(smem + 68096);
    float*    comb32 = (float*)(smem + 69120);
    ushort_t* gate4  = (ushort_t*)(smem + 69632);
    ushort_t* sbias  = (ushort_t*)(smem + 78080);

    const int b    = blockIdx.x;
    const int t    = threadIdx.x;
    const int wid  = t >> 6;
    const int lane = t & 63;
    const int l15  = lane & 15;
    const int lg   = lane >> 4;
    const int base = b * BSZ;

    // ---- phase 1: stage x -> bf16 swizzled; build gate4/sbias ------------
    for (int r = 0; r < 32; ++r) {
        float v = x[(size_t)(base + r) * CH + t];
        xb[r * 256 + (t ^ ((r & 7) << 3))] = f2b(v);
    }
    {
        float gwr[16], gbr[4];
        #pragma unroll
        for (int i = 0; i < 16; ++i) gwr[i] = gate_w[i];
        #pragma unroll
        for (int i = 0; i < 4; ++i)  gbr[i] = gate_b[i];
        for (int p = t; p < 32 * 33; p += 256) {
            int qi = p / 33, kj = p - qi * 33;
            float e0 = 0.f, e1 = 0.f, e2 = 0.f, e3 = 0.f;
            bool valid;
            bool fixed = (kj == 32) | (kj == qi);
            if (fixed) { e3 = 1.0f; valid = true; }
            else {
                int w = win[b * 1024 + qi * 32 + kj];
                valid = (w >= 0);
                if (valid) {
                    int rr = ei[w], cc = ei[E + w];
                    e0 = pos[cc * 3 + 0] - pos[rr * 3 + 0];
                    e1 = pos[cc * 3 + 1] - pos[rr * 3 + 1];
                    e2 = pos[cc * 3 + 2] - pos[rr * 3 + 2];
                    e3 = ev[w];
                }
            }
            float sb = valid ? (fixed ? 1.0f : e3) : -INFINITY;
            sbias[p] = f2b(sb);
            #pragma unroll
            for (int h = 0; h < 4; ++h) {
                float g = valid ? (e0 * gwr[h*4+0] + e1 * gwr[h*4+1] +
                                   e2 * gwr[h*4+2] + e3 * gwr[h*4+3] + gbr[h]) : 0.0f;
                gate4[p * 4 + h] = f2b(g);
            }
        }
    }
    __syncthreads();

    // ---- phase 2: qkv GEMM (swapped: C'[n][r] = sum_k W[n][k]·x[r][k]) ---
    {
        const int slB = (l15 & 7) << 3;
        #pragma unroll
        for (int mt = 0; mt < 12; ++mt) {
            int n0 = wid * 192 + mt * 16;
            const ushort_t* arow = qkv_wb + (size_t)(n0 + l15) * 256 + lg * 8;
            f32x4 acc0 = {0.f, 0.f, 0.f, 0.f};
            f32x4 acc1 = {0.f, 0.f, 0.f, 0.f};
            #pragma unroll
            for (int ks = 0; ks < 8; ++ks) {
                bf16x8 a  = *(const bf16x8*)(arow + ks * 32);
                int k0 = ks * 32 + lg * 8;
                bf16x8 b0 = *(const bf16x8*)&xb[l15 * 256 + (k0 ^ slB)];
                bf16x8 b1 = *(const bf16x8*)&xb[(16 + l15) * 256 + (k0 ^ slB)];
                acc0 = MFMA(a, b0, acc0);
                acc1 = MFMA(a, b1, acc1);
            }
            f32x4 bv = *(const f32x4*)(qkv_b + n0 + lg * 4);
            acc0 += bv; acc1 += bv;
            int sec = n0 >> 8;
            int c0  = (n0 & 255) + lg * 4;
            if (sec == 2) {                      // v -> vT[c][kj] (transposed)
                #pragma unroll
                for (int j = 0; j < 4; ++j) {
                    int c = c0 + j;
                    int sl = (c & 3) << 3;
                    vT[c * 32 + (l15 ^ sl)]        = f2b(acc0[j]);
                    vT[c * 32 + ((16 + l15) ^ sl)] = f2b(acc1[j]);
                }
            } else {                             // q / k row-major
                ushort_t* dst = (sec == 0) ? qb : kb;
                uint2 w0, w1;
                w0.x = pk2(acc0[0], acc0[1]); w0.y = pk2(acc0[2], acc0[3]);
                w1.x = pk2(acc1[0], acc1[1]); w1.y = pk2(acc1[2], acc1[3]);
                *(uint2*)&dst[l15 * 256 + (c0 ^ slB)]        = w0;
                *(uint2*)&dst[(16 + l15) * 256 + (c0 ^ slB)] = w1;
            }
        }
    }
    __syncthreads();

    // ---- phase 3: block-node rows via linearity (column means) -----------
    {
        int c = t;
        float s = 0.f;
        #pragma unroll
        for (int r = 0; r < 32; ++r) s += b2f(kb[r * 256 + (c ^ ((r & 7) << 3))]);
        krow32[c] = s * 0.03125f;
        float s2 = 0.f;
        int sl = (c & 3) << 3;
        #pragma unroll
        for (int kj = 0; kj < 32; ++kj) s2 += b2f(vT[c * 32 + (kj ^ sl)]);
        vrow32[c] = s2 * 0.03125f;
    }
    __syncthreads();

    // ---- phase 4: scores MFMA (wave = head). S[qi][kj], kj 0..31 ---------
    {
        int h = wid;
        const int slQ = (l15 & 7) << 3;
        f32x4 acc00 = {0.f,0.f,0.f,0.f}, acc01 = {0.f,0.f,0.f,0.f};
        f32x4 acc10 = {0.f,0.f,0.f,0.f}, acc11 = {0.f,0.f,0.f,0.f};
        #pragma unroll
        for (int ks = 0; ks < 2; ++ks) {
            int k0 = h * 64 + ks * 32 + lg * 8;
            bf16x8 aq0 = *(const bf16x8*)&qb[l15 * 256 + (k0 ^ slQ)];
            bf16x8 aq1 = *(const bf16x8*)&qb[(16 + l15) * 256 + (k0 ^ slQ)];
            bf16x8 bk0 = *(const bf16x8*)&kb[l15 * 256 + (k0 ^ slQ)];
            bf16x8 bk1 = *(const bf16x8*)&kb[(16 + l15) * 256 + (k0 ^ slQ)];
            acc00 = MFMA(aq0, bk0, acc00);
            acc01 = MFMA(aq0, bk1, acc01);
            acc10 = MFMA(aq1, bk0, acc10);
            acc11 = MFMA(aq1, bk1, acc11);
        }
        #pragma unroll
        for (int j = 0; j < 4; ++j) {
            int qiA = lg * 4 + j, qiB = 16 + lg * 4 + j;
            scf[(h * 32 + qiA) * SC_STRIDE + l15]      = acc00[j];
            scf[(h * 32 + qiA) * SC_STRIDE + 16 + l15] = acc01[j];
            scf[(h * 32 + qiB) * SC_STRIDE + l15]      = acc10[j];
            scf[(h * 32 + qiB) * SC_STRIDE + 16 + l15] = acc11[j];
        }
    }
    __syncthreads();

    // ---- phase 5: softmax + gate (128 threads: one per (qi,h)) -----------
    float rowv[33];
    const int qi5 = t >> 2, h5 = t & 3;
    if (t < 128) {
        #pragma unroll
        for (int kj = 0; kj < 32; ++kj)
            rowv[kj] = scf[(h5 * 32 + qi5) * SC_STRIDE + kj] * 0.125f
                     + b2f(sbias[qi5 * 33 + kj]);
        float s32 = 0.f;
        const int slQ5 = (qi5 & 7) << 3;
        #pragma unroll
        for (int k = 0; k < 64; ++k)
            s32 += b2f(qb[qi5 * 256 + ((h5 * 64 + k) ^ slQ5)]) * krow32[h5 * 64 + k];
        rowv[32] = s32 * 0.125f + 1.0f;

        float m = rowv[0];
        #pragma unroll
        for (int kj = 1; kj < 33; ++kj) m = fmaxf(m, rowv[kj]);
        float sum = 0.f;
        #pragma unroll
        for (int kj = 0; kj < 33; ++kj) { rowv[kj] = __expf(rowv[kj] - m); sum += rowv[kj]; }
        float inv = 1.0f / sum;
        #pragma unroll
        for (int kj = 0; kj < 33; ++kj)
            rowv[kj] = rowv[kj] * inv + b2f(gate4[(qi5 * 33 + kj) * 4 + h5]);
    }
    __syncthreads();   // all scf reads done before comb overwrites region
    if (t < 128) {
        const int slC = (qi5 & 3) << 3;
        #pragma unroll
        for (int kj = 0; kj < 32; ++kj)
            comb[(h5 * 32 + qi5) * 32 + (kj ^ slC)] = f2b(rowv[kj]);
        comb32[h5 * 32 + qi5] = rowv[32];
    }
    __syncthreads();

    // ---- phase 6: PV MFMA (swapped: X^T[c][qi]) + block-node fixup -------
    {
        int h = wid;
        const int slC6 = (l15 & 3) << 3;
        #pragma unroll
        for (int ct = 0; ct < 4; ++ct) {
            int cbase = h * 64 + ct * 16;
            bf16x8 a = *(const bf16x8*)&vT[(cbase + l15) * 32 + ((lg * 8) ^ slC6)];
            #pragma unroll
            for (int qt = 0; qt < 2; ++qt) {
                bf16x8 bfr = *(const bf16x8*)&comb[(h * 32 + qt * 16 + l15) * 32
                                                   + ((lg * 8) ^ slC6)];
                f32x4 acc = {0.f, 0.f, 0.f, 0.f};
                acc = MFMA(a, bfr, acc);
                int qi = qt * 16 + l15;
                float c32 = comb32[h * 32 + qi];
                float r0 = acc[0] + c32 * vrow32[cbase + lg * 4 + 0];
                float r1 = acc[1] + c32 * vrow32[cbase + lg * 4 + 1];
                float r2 = acc[2] + c32 * vrow32[cbase + lg * 4 + 2];
                float r3 = acc[3] + c32 * vrow32[cbase + lg * 4 + 3];
                int c0w = cbase + lg * 4;
                int slR = (l15 & 7) << 3;   // qi&7 == l15&7
                uint2 wv; wv.x = pk2(r0, r1); wv.y = pk2(r2, r3);
                *(uint2*)&xo[qi * 256 + (c0w ^ slR)] = wv;
            }
        }
    }
    __syncthreads();

    // ---- phase 7: proj MFMA (swapped) + fp32 global write ----------------
    {
        const int slR = (l15 & 7) << 3;
        #pragma unroll
        for (int mt = 0; mt < 4; ++mt) {
            int n0 = wid * 64 + mt * 16;
            const ushort_t* arow = proj_wb + (size_t)(n0 + l15) * 256 + lg * 8;
            f32x4 acc0 = {0.f, 0.f, 0.f, 0.f};
            f32x4 acc1 = {0.f, 0.f, 0.f, 0.f};
            #pragma unroll
            for (int ks = 0; ks < 8; ++ks) {
                bf16x8 a  = *(const bf16x8*)(arow + ks * 32);
                int k0 = ks * 32 + lg * 8;
                bf16x8 b0 = *(const bf16x8*)&xo[l15 * 256 + (k0 ^ slR)];
                bf16x8 b1 = *(const bf16x8*)&xo[(16 + l15) * 256 + (k0 ^ slR)];
                acc0 = MFMA(a, b0, acc0);
                acc1 = MFMA(a, b1, acc1);
            }
            f32x4 bv = *(const f32x4*)(proj_b + n0 + lg * 4);
            acc0 += bv; acc1 += bv;
            int c0 = n0 + lg * 4;
            *(f32x4*)(out + (size_t)(base + l15) * 256 + c0)      = acc0;
            *(f32x4*)(out + (size_t)(base + 16 + l15) * 256 + c0) = acc1;
        }
    }
}

extern "C" void kernel_launch(void* const* d_in, const int* in_sizes, int n_in,
                              void* d_out, int out_size, void* d_ws, size_t ws_size,
                              hipStream_t stream) {
    const float* x      = (const float*)d_in[0];
    const int*   ei     = (const int*)  d_in[1];
    const float* ev     = (const float*)d_in[2];
    const float* pos    = (const float*)d_in[3];
    const float* qkv_w  = (const float*)d_in[4];
    const float* qkv_b  = (const float*)d_in[5];
    const float* proj_w = (const float*)d_in[6];
    const float* proj_b = (const float*)d_in[7];
    const float* gate_w = (const float*)d_in[8];
    const float* gate_b = (const float*)d_in[9];
    float* out = (float*)d_out;

    const int E  = in_sizes[2];
    const int N  = in_sizes[0] / CH;
    const int nb = N / BSZ;

    size_t win_bytes = (size_t)nb * BSZ * BSZ * sizeof(int);
    int* win = (int*)d_ws;
    ushort_t* qkv_wb  = (ushort_t*)((char*)d_ws + win_bytes);
    ushort_t* proj_wb = qkv_wb + 768 * 256;

    hipMemsetAsync(win, 0xFF, win_bytes, stream);
    edge_win_kernel<<<(E + 255) / 256, 256, 0, stream>>>(ei, E, nb, win);
    wconv_kernel<<<768, 256, 0, stream>>>(qkv_w, proj_w, qkv_wb, proj_wb);
    leaf_attn_mfma<<<nb, 256, 0, stream>>>(x, ei, ev, pos, qkv_wb, qkv_b,
                                           proj_wb, proj_b, gate_w, gate_b,
                                           win, out, E, nb);
}